// Round 2
// baseline (482.331 us; speedup 1.0000x reference)
//
#include <hip/hip_runtime.h>
#include <stdint.h>

// Problem constants (from reference)
#define B_    256
#define NR    64
#define NW    64
#define DIN   512
#define NH    8
#define DK    64
#define E_    512          // NH*DK
#define TEMP_INV 0.125f    // 1/sqrt(64)
#define EPSV  1e-7f

typedef unsigned short u16;
typedef __attribute__((ext_vector_type(4))) float  floatx4;
typedef __attribute__((ext_vector_type(8))) short  shortx8;
typedef __attribute__((ext_vector_type(4))) short  shortx4;

__device__ __forceinline__ u16 f2bf(float f) {
    union { float f; unsigned u; } c; c.f = f;
    unsigned r = c.u + 0x7FFFu + ((c.u >> 16) & 1u);   // RNE
    return (u16)(r >> 16);
}
__device__ __forceinline__ float bf2f(u16 u) {
    union { unsigned u; float f; } c; c.u = ((unsigned)u) << 16; return c.f;
}

// ---------------------------------------------------------------------------
// Kernel 1: grouped projection GEMM in SPLIT-BF16 (effective ~fp32 precision).
// x = hi + lo (both bf16); acc += Ah*Bh + Ah*Bl + Al*Bh  (lo*lo ~2^-18, dropped)
// For group n: out[b, e] = sum_d X[b, n, d] * W[n, d, e].
//   z=0: q -> qp (fp32)    z=1: k -> kp (fp32)
//   z=2: v -> atomicAdd into vsum[b,e] (sum over n), vp never materialized.
// Tile: 128x128 per block, BK=32, 4 waves of 64x64 (4x4 of 16x16x32 MFMA).
// ---------------------------------------------------------------------------
#define PST 36

__global__ __launch_bounds__(256)
void proj_kernel(const float* __restrict__ q, const float* __restrict__ kk_,
                 const float* __restrict__ v,
                 const float* __restrict__ Wq, const float* __restrict__ Wk,
                 const float* __restrict__ Wv,
                 float* __restrict__ qp, float* __restrict__ kp,
                 float* __restrict__ vsum)
{
    const float* X; const float* W; float* dst = nullptr; bool vmode = false;
    if (blockIdx.z == 0)      { X = q;   W = Wq; dst = qp; }
    else if (blockIdx.z == 1) { X = kk_; W = Wk; dst = kp; }
    else                      { X = v;   W = Wv; vmode = true; }

    const int n  = blockIdx.y;
    const int m0 = (blockIdx.x >> 2) * 128;
    const int n0 = (blockIdx.x & 3) * 128;

    __shared__ u16 Ah[128 * PST];
    __shared__ u16 Al[128 * PST];
    __shared__ u16 Bh[128 * PST];
    __shared__ u16 Bl[128 * PST];

    const int tid  = threadIdx.x;
    const int lane = tid & 63;
    const int wave = tid >> 6;
    const int wm   = (wave >> 1) * 64;
    const int wn   = (wave & 1) * 64;
    const int l15  = lane & 15;
    const int quad = lane >> 4;

    floatx4 acc[4][4];
#pragma unroll
    for (int i = 0; i < 4; i++)
#pragma unroll
        for (int j = 0; j < 4; j++) acc[i][j] = (floatx4){0.f, 0.f, 0.f, 0.f};

    const int arow  = tid >> 1;
    const int ahalf = tid & 1;
    const float* aptr  = X + ((size_t)(m0 + arow) * NW + n) * DIN + ahalf * 16;
    const float* wbase = W + (size_t)n * (DIN * E_) + n0;

    for (int k0 = 0; k0 < DIN; k0 += 32) {
        // ---- stage A: 128 rows x 32 k, fp32 -> (hi, lo) bf16 ----
#pragma unroll
        for (int c = 0; c < 4; c++) {
            floatx4 av = *(const floatx4*)(aptr + k0 + c * 4);
            u16 h0 = f2bf(av.x), h1 = f2bf(av.y), h2 = f2bf(av.z), h3 = f2bf(av.w);
            shortx4 ph = { (short)h0, (short)h1, (short)h2, (short)h3 };
            shortx4 pl = { (short)f2bf(av.x - bf2f(h0)), (short)f2bf(av.y - bf2f(h1)),
                           (short)f2bf(av.z - bf2f(h2)), (short)f2bf(av.w - bf2f(h3)) };
            *(shortx4*)&Ah[arow * PST + ahalf * 16 + c * 4] = ph;
            *(shortx4*)&Al[arow * PST + ahalf * 16 + c * 4] = pl;
        }
        // ---- stage B transposed: Bs[e][k] = W[k0+k][n0+e], hi/lo ----
#pragma unroll
        for (int s = 0; s < 16; s++) {
            int flat = s * 256 + tid;
            int kk2 = flat >> 7;         // 0..31
            int ec  = flat & 127;        // 0..127 (lanes -> consecutive ec: coalesced)
            float wv = wbase[(size_t)(k0 + kk2) * E_ + ec];
            u16 hh = f2bf(wv);
            Bh[ec * PST + kk2] = hh;
            Bl[ec * PST + kk2] = f2bf(wv - bf2f(hh));
        }
        __syncthreads();

        shortx8 afh[4], afl[4], bfh[4], bfl[4];
#pragma unroll
        for (int mi = 0; mi < 4; mi++) {
            const u16* ph = &Ah[(wm + mi * 16 + l15) * PST + quad * 8];
            const u16* pl = &Al[(wm + mi * 16 + l15) * PST + quad * 8];
            shortx4 lo1 = *(const shortx4*)ph, hi1 = *(const shortx4*)(ph + 4);
            shortx4 lo2 = *(const shortx4*)pl, hi2 = *(const shortx4*)(pl + 4);
            afh[mi] = __builtin_shufflevector(lo1, hi1, 0, 1, 2, 3, 4, 5, 6, 7);
            afl[mi] = __builtin_shufflevector(lo2, hi2, 0, 1, 2, 3, 4, 5, 6, 7);
        }
#pragma unroll
        for (int ni = 0; ni < 4; ni++) {
            const u16* ph = &Bh[(wn + ni * 16 + l15) * PST + quad * 8];
            const u16* pl = &Bl[(wn + ni * 16 + l15) * PST + quad * 8];
            shortx4 lo1 = *(const shortx4*)ph, hi1 = *(const shortx4*)(ph + 4);
            shortx4 lo2 = *(const shortx4*)pl, hi2 = *(const shortx4*)(pl + 4);
            bfh[ni] = __builtin_shufflevector(lo1, hi1, 0, 1, 2, 3, 4, 5, 6, 7);
            bfl[ni] = __builtin_shufflevector(lo2, hi2, 0, 1, 2, 3, 4, 5, 6, 7);
        }
#pragma unroll
        for (int mi = 0; mi < 4; mi++)
#pragma unroll
            for (int ni = 0; ni < 4; ni++) {
                acc[mi][ni] = __builtin_amdgcn_mfma_f32_16x16x32_bf16(
                    afh[mi], bfh[ni], acc[mi][ni], 0, 0, 0);
                acc[mi][ni] = __builtin_amdgcn_mfma_f32_16x16x32_bf16(
                    afh[mi], bfl[ni], acc[mi][ni], 0, 0, 0);
                acc[mi][ni] = __builtin_amdgcn_mfma_f32_16x16x32_bf16(
                    afl[mi], bfh[ni], acc[mi][ni], 0, 0, 0);
            }
        __syncthreads();
    }

    // Epilogue: C/D layout col = lane&15, row = quad*4 + reg  [measured m89]
    if (!vmode) {
#pragma unroll
        for (int mi = 0; mi < 4; mi++) {
            int rowb = m0 + wm + mi * 16 + quad * 4;
#pragma unroll
            for (int ni = 0; ni < 4; ni++) {
                int col = n0 + wn + ni * 16 + l15;
#pragma unroll
                for (int r = 0; r < 4; r++)
                    dst[((size_t)(rowb + r) * NW + n) * E_ + col] = acc[mi][ni][r];
            }
        }
    } else {
#pragma unroll
        for (int mi = 0; mi < 4; mi++) {
            int rowb = m0 + wm + mi * 16 + quad * 4;
#pragma unroll
            for (int ni = 0; ni < 4; ni++) {
                int col = n0 + wn + ni * 16 + l15;
#pragma unroll
                for (int r = 0; r < 4; r++)
                    atomicAdd(&vsum[(size_t)(rowb + r) * E_ + col], acc[mi][ni][r]);
            }
        }
    }
}

// ---------------------------------------------------------------------------
// Kernel 2: per-(h,b): fp32 scores (VALU), row-max, double-exp softmax over
// the 64 query rows, top-16 threshold sparsification -> attnT[b][j][h].
// One wave per block; lane j owns query row j.
// ---------------------------------------------------------------------------
__global__ __launch_bounds__(64)
void attn_kernel(const float* __restrict__ qp, const float* __restrict__ kp,
                 float* __restrict__ attnT)
{
    const int h = blockIdx.x >> 8;
    const int b = blockIdx.x & 255;

    __shared__ float qs[64 * 65];
    __shared__ float ks[64 * 65];

    const int lane = threadIdx.x;
    const int r0 = lane >> 4;          // 0..3
    const int c4 = (lane & 15) * 4;    // 0..60

#pragma unroll
    for (int i = 0; i < 16; i++) {
        int row = i * 4 + r0;
        floatx4 qv = *(const floatx4*)&qp[((size_t)(b * NR + row)) * E_ + h * DK + c4];
        floatx4 kv = *(const floatx4*)&kp[((size_t)(b * NW + row)) * E_ + h * DK + c4];
        qs[row * 65 + c4 + 0] = qv.x; qs[row * 65 + c4 + 1] = qv.y;
        qs[row * 65 + c4 + 2] = qv.z; qs[row * 65 + c4 + 3] = qv.w;
        ks[row * 65 + c4 + 0] = kv.x; ks[row * 65 + c4 + 1] = kv.y;
        ks[row * 65 + c4 + 2] = kv.z; ks[row * 65 + c4 + 3] = kv.w;
    }
    __syncthreads();

    float qreg[64];
#pragma unroll
    for (int c = 0; c < 64; c++) qreg[c] = qs[lane * 65 + c];

    float m = -1e30f;
#pragma unroll 4
    for (int l = 0; l < 64; l++) {
        float s = 0.f;
#pragma unroll
        for (int c = 0; c < 64; c++) s = fmaf(qreg[c], ks[l * 65 + c], s);
        m = fmaxf(m, s);
    }
    m *= TEMP_INV;

    // lane j owns query row j: a = exp(max score), softmax over 64 rows
    float e = expf(m);
    float mx = e;
#pragma unroll
    for (int d = 1; d < 64; d <<= 1) mx = fmaxf(mx, __shfl_xor(mx, d));
    float t = expf(e - mx);
    float S = t;
#pragma unroll
    for (int d = 1; d < 64; d <<= 1) S += __shfl_xor(S, d);
    float s = t / S;

    // k-th largest (k=16) via 16x (wave-max, mask first holder)
    float cur = s, v16 = 0.f;
    for (int it = 0; it < 16; it++) {
        float mv = cur;
#pragma unroll
        for (int d = 1; d < 64; d <<= 1) mv = fmaxf(mv, __shfl_xor(mv, d));
        unsigned long long bal = __ballot(cur == mv);
        int first = __ffsll(bal) - 1;
        if (lane == first) cur = -1e30f;
        v16 = mv;
    }
    float delta = v16 + EPSV;
    float w = fmaxf(s - delta, 0.f);
    float sw = w;
#pragma unroll
    for (int d = 1; d < 64; d <<= 1) sw += __shfl_xor(sw, d);
    attnT[((size_t)b * NR + lane) * NH + h] = w / (sw + EPSV);
}

// ---------------------------------------------------------------------------
// Kernel 3: fcv[b,h,o] = sum_dv vsum[b, h*64+dv] * W[o, h*64+dv]
// grid (8: ohalf*4+bq, 8: h, 2: fc/gate), 256 threads (one per o in half)
// ---------------------------------------------------------------------------
__global__ __launch_bounds__(256)
void fcv_kernel(const float* __restrict__ vsum, const float* __restrict__ fc_w,
                const float* __restrict__ gate_w, float* __restrict__ fcv,
                float* __restrict__ gatev)
{
    const int ohalf = blockIdx.x >> 2;
    const int bq    = blockIdx.x & 3;
    const int h     = blockIdx.y;
    const float* W  = blockIdx.z ? gate_w : fc_w;
    float* out      = blockIdx.z ? gatev : fcv;
    const int o     = ohalf * 256 + threadIdx.x;

    __shared__ float vs[64 * 64];
#pragma unroll
    for (int i = 0; i < 16; i++) {
        int idx = i * 256 + threadIdx.x;
        int bb = idx >> 6, d = idx & 63;
        vs[idx] = vsum[(size_t)(bq * 64 + bb) * E_ + h * DK + d];
    }
    floatx4 wr[16];
#pragma unroll
    for (int c = 0; c < 16; c++)
        wr[c] = *(const floatx4*)(W + (size_t)o * E_ + h * DK + c * 4);
    __syncthreads();

    for (int bb = 0; bb < 64; bb++) {
        const floatx4* vr = (const floatx4*)&vs[bb * 64];
        float a = 0.f;
#pragma unroll
        for (int c = 0; c < 16; c++) {
            floatx4 vv = vr[c];
            a += vv.x * wr[c].x + vv.y * wr[c].y + vv.z * wr[c].z + vv.w * wr[c].w;
        }
        out[((size_t)(bq * 64 + bb) * NH + h) * E_ + o] = a;
    }
}

// ---------------------------------------------------------------------------
// Kernel 4: out[b,r,o] = sigmoid(gate_lin) * tanh(fc_lin),
//   fc_lin = sum_h attnT[b,r,h]*fcv[b,h,o] + fc_b[o]   (same for gate)
// ---------------------------------------------------------------------------
__global__ __launch_bounds__(256)
void final_kernel(const float* __restrict__ fcv, const float* __restrict__ gatev,
                  const float* __restrict__ attnT, const float* __restrict__ fc_b,
                  const float* __restrict__ gate_b, float* __restrict__ out)
{
    const int b = blockIdx.x;
    __shared__ float fcs[NH * E_];
    __shared__ float gts[NH * E_];
    __shared__ float ats[NR * NH];
    const int tid = threadIdx.x;

#pragma unroll
    for (int i = 0; i < 16; i++) {
        fcs[i * 256 + tid] = fcv[(size_t)b * NH * E_ + i * 256 + tid];
        gts[i * 256 + tid] = gatev[(size_t)b * NH * E_ + i * 256 + tid];
    }
    ats[tid]       = attnT[(size_t)b * NR * NH + tid];
    ats[256 + tid] = attnT[(size_t)b * NR * NH + 256 + tid];
    __syncthreads();

    float bfc0 = fc_b[tid],   bfc1 = fc_b[256 + tid];
    float bgt0 = gate_b[tid], bgt1 = gate_b[256 + tid];

    for (int r = 0; r < NR; r++) {
#pragma unroll
        for (int half = 0; half < 2; half++) {
            int o = half * 256 + tid;
            float fc = half ? bfc1 : bfc0;
            float gt = half ? bgt1 : bgt0;
#pragma unroll
            for (int hh = 0; hh < NH; hh++) {
                float a = ats[r * NH + hh];
                fc += a * fcs[hh * E_ + o];
                gt += a * gts[hh * E_ + o];
            }
            float g = 1.f / (1.f + expf(-gt));
            out[((size_t)(b * NR + r)) * E_ + o] = g * tanhf(fc);
        }
    }
}

// ---------------------------------------------------------------------------
extern "C" void kernel_launch(void* const* d_in, const int* in_sizes, int n_in,
                              void* d_out, int out_size, void* d_ws, size_t ws_size,
                              hipStream_t stream)
{
    const float* q      = (const float*)d_in[0];
    const float* k      = (const float*)d_in[1];
    const float* v      = (const float*)d_in[2];
    const float* Wq     = (const float*)d_in[3];
    const float* Wk     = (const float*)d_in[4];
    const float* Wv     = (const float*)d_in[5];
    const float* fc_w   = (const float*)d_in[6];
    const float* fc_b   = (const float*)d_in[7];
    const float* gate_w = (const float*)d_in[8];
    const float* gate_b = (const float*)d_in[9];
    float* out = (float*)d_out;

    // workspace layout (~73 MB)
    char* ws = (char*)d_ws;
    float* qp    = (float*)(ws);                               // 32 MB
    float* kp    = (float*)(ws + 33554432);                    // 32 MB
    float* vsum  = (float*)(ws + 67108864);                    // 512 KB
    float* attnT = (float*)(ws + 67108864 + 524288);           // 512 KB
    float* fcv   = (float*)(ws + 67108864 + 2 * 524288);       // 4 MB
    float* gatev = (float*)(ws + 67108864 + 2 * 524288 + 4194304); // 4 MB

    hipMemsetAsync(vsum, 0, 524288, stream);

    hipLaunchKernelGGL(proj_kernel, dim3(8, 64, 3), dim3(256), 0, stream,
                       q, k, v, Wq, Wk, Wv, qp, kp, vsum);
    hipLaunchKernelGGL(attn_kernel, dim3(2048), dim3(64), 0, stream, qp, kp, attnT);
    hipLaunchKernelGGL(fcv_kernel, dim3(8, 8, 2), dim3(256), 0, stream,
                       vsum, fc_w, gate_w, fcv, gatev);
    hipLaunchKernelGGL(final_kernel, dim3(256), dim3(256), 0, stream,
                       fcv, gatev, attnT, fc_b, gate_b, out);
}

// Round 3
// 426.217 us; speedup vs baseline: 1.1317x; 1.1317x over previous
//
#include <hip/hip_runtime.h>
#include <stdint.h>

// Problem constants (from reference)
#define B_    256
#define NR    64
#define NW    64
#define DIN   512
#define NH    8
#define DK    64
#define E_    512          // NH*DK
#define TEMP_INV 0.125f    // 1/sqrt(64)
#define EPSV  1e-7f

typedef unsigned short u16;
typedef unsigned int   u32;
typedef __attribute__((ext_vector_type(4))) float  floatx4;
typedef __attribute__((ext_vector_type(8))) short  shortx8;
typedef __attribute__((ext_vector_type(4))) short  shortx4;
typedef __attribute__((ext_vector_type(2))) u32    uintx2;

__device__ __forceinline__ u32 asu(float f) { union { float f; u32 u; } c; c.f = f; return c.u; }
__device__ __forceinline__ float asf(u32 u) { union { u32 u; float f; } c; c.u = u; return c.f; }

// pack truncated-bf16 of (x, y) into one dword: low16 = hi16(x), high16 = hi16(y)
__device__ __forceinline__ u32 packhi(u32 x, u32 y) {
    return (x >> 16) | (y & 0xFFFF0000u);
}

// ---------------------------------------------------------------------------
// Kernel 1: grouped projection GEMM in SPLIT-BF16 (truncation split; effective
// ~2^-15 relative accuracy).  x = hi + lo;  acc += Ah*Bh + Ah*Bl + Al*Bh.
// For group n: out[b, e] = sum_d X[b, n, d] * W[n, d, e].
//   z=0: q -> qp (fp32)    z=1: k -> kp (fp32)
//   z=2: v -> atomicAdd into vsum[b,e], PLAIN bf16 (hi*hi only).
// Tile: 128x128 per block, BK=32, 4 waves of 64x64.  Register-prefetched
// global loads (software pipeline) hide VMEM latency across the MFMA phase.
// ---------------------------------------------------------------------------
#define PST 40   // u16 row stride: 80 B rows, 16-B aligned -> ds_read_b128 frags

__global__ __launch_bounds__(256)
void proj_kernel(const float* __restrict__ q, const float* __restrict__ kk_,
                 const float* __restrict__ v,
                 const float* __restrict__ Wq, const float* __restrict__ Wk,
                 const float* __restrict__ Wv,
                 float* __restrict__ qp, float* __restrict__ kp,
                 float* __restrict__ vsum)
{
    const float* X; const float* W; float* dst = nullptr; bool vmode = false;
    if (blockIdx.z == 0)      { X = q;   W = Wq; dst = qp; }
    else if (blockIdx.z == 1) { X = kk_; W = Wk; dst = kp; }
    else                      { X = v;   W = Wv; vmode = true; }

    const int n  = blockIdx.y;
    const int m0 = (blockIdx.x >> 2) * 128;
    const int n0 = (blockIdx.x & 3) * 128;

    __shared__ u16 Ah[128 * PST];
    __shared__ u16 Al[128 * PST];
    __shared__ u16 Bh[128 * PST];
    __shared__ u16 Bl[128 * PST];

    const int tid  = threadIdx.x;
    const int lane = tid & 63;
    const int wave = tid >> 6;
    const int wm   = (wave >> 1) * 64;
    const int wn   = (wave & 1) * 64;
    const int l15  = lane & 15;
    const int quad = lane >> 4;

    floatx4 acc[4][4];
#pragma unroll
    for (int i = 0; i < 4; i++)
#pragma unroll
        for (int j = 0; j < 4; j++) acc[i][j] = (floatx4){0.f, 0.f, 0.f, 0.f};

    // A staging: thread -> row (tid>>1), half (tid&1)*16, 16 elems (4 float4)
    const int arow  = tid >> 1;
    const int ahalf = tid & 1;
    const float* aptr = X + ((size_t)(m0 + arow) * NW + n) * DIN + ahalf * 16;
    // B staging: thread -> 4x4 patch: rows kgrp*4+j, cols ec0..ec0+3
    const int ec0  = (tid & 31) * 4;
    const int kgrp = tid >> 5;                 // 0..7
    const float* wbase = W + (size_t)n * (DIN * E_) + n0 + ec0;

    floatx4 pa[4], pb[4];
#pragma unroll
    for (int c = 0; c < 4; c++) pa[c] = *(const floatx4*)(aptr + c * 4);
#pragma unroll
    for (int j = 0; j < 4; j++) pb[j] = *(const floatx4*)(wbase + (size_t)(kgrp * 4 + j) * E_);

    for (int it = 0; it < 16; it++) {
        const int k0 = it * 32;

        // ---- convert + write LDS from prefetched regs ----
#pragma unroll
        for (int c = 0; c < 4; c++) {
            u32 x = asu(pa[c].x), y = asu(pa[c].y), z = asu(pa[c].z), w = asu(pa[c].w);
            u32 h01 = packhi(x, y), h23 = packhi(z, w);
            float r0 = pa[c].x - asf(x & 0xFFFF0000u);
            float r1 = pa[c].y - asf(y & 0xFFFF0000u);
            float r2 = pa[c].z - asf(z & 0xFFFF0000u);
            float r3 = pa[c].w - asf(w & 0xFFFF0000u);
            u32 l01 = packhi(asu(r0), asu(r1)), l23 = packhi(asu(r2), asu(r3));
            *(uintx2*)&Ah[arow * PST + ahalf * 16 + c * 4] = (uintx2){h01, h23};
            if (!vmode)
                *(uintx2*)&Al[arow * PST + ahalf * 16 + c * 4] = (uintx2){l01, l23};
        }
#pragma unroll
        for (int e = 0; e < 4; e++) {
            u32 x0 = asu(pb[0][e]), x1 = asu(pb[1][e]), x2 = asu(pb[2][e]), x3 = asu(pb[3][e]);
            u32 h01 = packhi(x0, x1), h23 = packhi(x2, x3);
            *(uintx2*)&Bh[(ec0 + e) * PST + kgrp * 4] = (uintx2){h01, h23};
            if (!vmode) {
                float r0 = pb[0][e] - asf(x0 & 0xFFFF0000u);
                float r1 = pb[1][e] - asf(x1 & 0xFFFF0000u);
                float r2 = pb[2][e] - asf(x2 & 0xFFFF0000u);
                float r3 = pb[3][e] - asf(x3 & 0xFFFF0000u);
                u32 l01 = packhi(asu(r0), asu(r1)), l23 = packhi(asu(r2), asu(r3));
                *(uintx2*)&Bl[(ec0 + e) * PST + kgrp * 4] = (uintx2){l01, l23};
            }
        }

        // ---- issue next iteration's global loads (land during MFMA phase) ----
        if (it < 15) {
            const int kn = k0 + 32;
#pragma unroll
            for (int c = 0; c < 4; c++) pa[c] = *(const floatx4*)(aptr + kn + c * 4);
#pragma unroll
            for (int j = 0; j < 4; j++)
                pb[j] = *(const floatx4*)(wbase + (size_t)(kn + kgrp * 4 + j) * E_);
        }

        __syncthreads();

        shortx8 afh[4], afl[4], bfh[4], bfl[4];
#pragma unroll
        for (int mi = 0; mi < 4; mi++) {
            afh[mi] = *(const shortx8*)&Ah[(wm + mi * 16 + l15) * PST + quad * 8];
            if (!vmode)
                afl[mi] = *(const shortx8*)&Al[(wm + mi * 16 + l15) * PST + quad * 8];
        }
#pragma unroll
        for (int ni = 0; ni < 4; ni++) {
            bfh[ni] = *(const shortx8*)&Bh[(wn + ni * 16 + l15) * PST + quad * 8];
            if (!vmode)
                bfl[ni] = *(const shortx8*)&Bl[(wn + ni * 16 + l15) * PST + quad * 8];
        }
#pragma unroll
        for (int mi = 0; mi < 4; mi++)
#pragma unroll
            for (int ni = 0; ni < 4; ni++) {
                acc[mi][ni] = __builtin_amdgcn_mfma_f32_16x16x32_bf16(
                    afh[mi], bfh[ni], acc[mi][ni], 0, 0, 0);
                if (!vmode) {
                    acc[mi][ni] = __builtin_amdgcn_mfma_f32_16x16x32_bf16(
                        afh[mi], bfl[ni], acc[mi][ni], 0, 0, 0);
                    acc[mi][ni] = __builtin_amdgcn_mfma_f32_16x16x32_bf16(
                        afl[mi], bfh[ni], acc[mi][ni], 0, 0, 0);
                }
            }
        __syncthreads();
    }

    // Epilogue: C/D layout col = lane&15, row = quad*4 + reg  [measured m89]
    if (!vmode) {
#pragma unroll
        for (int mi = 0; mi < 4; mi++) {
            int rowb = m0 + wm + mi * 16 + quad * 4;
#pragma unroll
            for (int ni = 0; ni < 4; ni++) {
                int col = n0 + wn + ni * 16 + l15;
#pragma unroll
                for (int r = 0; r < 4; r++)
                    dst[((size_t)(rowb + r) * NW + n) * E_ + col] = acc[mi][ni][r];
            }
        }
    } else {
#pragma unroll
        for (int mi = 0; mi < 4; mi++) {
            int rowb = m0 + wm + mi * 16 + quad * 4;
#pragma unroll
            for (int ni = 0; ni < 4; ni++) {
                int col = n0 + wn + ni * 16 + l15;
#pragma unroll
                for (int r = 0; r < 4; r++)
                    atomicAdd(&vsum[(size_t)(rowb + r) * E_ + col], acc[mi][ni][r]);
            }
        }
    }
}

// ---------------------------------------------------------------------------
// Kernel 2: per-(h,b): fp32 scores, 256 threads = 4 waves; wave w handles
// l in [w*16, w*16+16); lane j owns query row j.  Cross-wave max via LDS,
// then wave 0 does double-exp softmax over 64 rows + top-16 threshold.
// ---------------------------------------------------------------------------
__global__ __launch_bounds__(256)
void attn_kernel(const float* __restrict__ qp, const float* __restrict__ kp,
                 float* __restrict__ attnT)
{
    const int h = blockIdx.x >> 8;
    const int b = blockIdx.x & 255;

    __shared__ float qs[64 * 68];
    __shared__ float ks[64 * 68];
    __shared__ float mred[4][64];

    const int t    = threadIdx.x;
    const int w    = t >> 6;
    const int lane = t & 63;

    // stage q,k 64x64 fp32 (coalesced float4)
#pragma unroll
    for (int s = 0; s < 4; s++) {
        int f = s * 256 + t;
        int row = f >> 4, c4 = (f & 15) * 4;
        *(floatx4*)&qs[row * 68 + c4] =
            *(const floatx4*)&qp[((size_t)(b * NR + row)) * E_ + h * DK + c4];
        *(floatx4*)&ks[row * 68 + c4] =
            *(const floatx4*)&kp[((size_t)(b * NW + row)) * E_ + h * DK + c4];
    }
    __syncthreads();

    floatx4 qr[16];
#pragma unroll
    for (int c = 0; c < 16; c++) qr[c] = *(const floatx4*)&qs[lane * 68 + c * 4];

    float mloc = -1e30f;
#pragma unroll 4
    for (int ll = 0; ll < 16; ll++) {
        int l = w * 16 + ll;
        floatx4 a4 = (floatx4){0.f, 0.f, 0.f, 0.f};
#pragma unroll
        for (int c = 0; c < 16; c++) {
            floatx4 kv = *(const floatx4*)&ks[l * 68 + c * 4];
            a4.x = fmaf(qr[c].x, kv.x, a4.x);
            a4.y = fmaf(qr[c].y, kv.y, a4.y);
            a4.z = fmaf(qr[c].z, kv.z, a4.z);
            a4.w = fmaf(qr[c].w, kv.w, a4.w);
        }
        float s = (a4.x + a4.y) + (a4.z + a4.w);
        mloc = fmaxf(mloc, s);
    }
    mred[w][lane] = mloc;
    __syncthreads();

    if (t < 64) {   // wave 0 only
        float m = fmaxf(fmaxf(mred[0][lane], mred[1][lane]),
                        fmaxf(mred[2][lane], mred[3][lane])) * TEMP_INV;
        // a = exp(max score); stable softmax over the 64 query rows
        float e = expf(m);
        float mx = e;
#pragma unroll
        for (int d = 1; d < 64; d <<= 1) mx = fmaxf(mx, __shfl_xor(mx, d));
        float tt = expf(e - mx);
        float S = tt;
#pragma unroll
        for (int d = 1; d < 64; d <<= 1) S += __shfl_xor(S, d);
        float s = tt / S;

        // k-th largest (k=16) via 16x (wave-max, mask first holder)
        float cur = s, v16 = 0.f;
        for (int itk = 0; itk < 16; itk++) {
            float mv = cur;
#pragma unroll
            for (int d = 1; d < 64; d <<= 1) mv = fmaxf(mv, __shfl_xor(mv, d));
            unsigned long long bal = __ballot(cur == mv);
            int first = __ffsll(bal) - 1;
            if (lane == first) cur = -1e30f;
            v16 = mv;
        }
        float delta = v16 + EPSV;
        float ww = fmaxf(s - delta, 0.f);
        float sw = ww;
#pragma unroll
        for (int d = 1; d < 64; d <<= 1) sw += __shfl_xor(sw, d);
        attnT[((size_t)b * NR + lane) * NH + h] = ww / (sw + EPSV);
    }
}

// ---------------------------------------------------------------------------
// Kernel 3: fcv[b,h,o] = sum_dv vsum[b, h*64+dv] * W[o, h*64+dv]
// ---------------------------------------------------------------------------
__global__ __launch_bounds__(256)
void fcv_kernel(const float* __restrict__ vsum, const float* __restrict__ fc_w,
                const float* __restrict__ gate_w, float* __restrict__ fcv,
                float* __restrict__ gatev)
{
    const int ohalf = blockIdx.x >> 2;
    const int bq    = blockIdx.x & 3;
    const int h     = blockIdx.y;
    const float* W  = blockIdx.z ? gate_w : fc_w;
    float* out      = blockIdx.z ? gatev : fcv;
    const int o     = ohalf * 256 + threadIdx.x;

    __shared__ float vs[64 * 64];
#pragma unroll
    for (int i = 0; i < 16; i++) {
        int idx = i * 256 + threadIdx.x;
        int bb = idx >> 6, d = idx & 63;
        vs[idx] = vsum[(size_t)(bq * 64 + bb) * E_ + h * DK + d];
    }
    floatx4 wr[16];
#pragma unroll
    for (int c = 0; c < 16; c++)
        wr[c] = *(const floatx4*)(W + (size_t)o * E_ + h * DK + c * 4);
    __syncthreads();

    for (int bb = 0; bb < 64; bb++) {
        const floatx4* vr = (const floatx4*)&vs[bb * 64];
        float a = 0.f;
#pragma unroll
        for (int c = 0; c < 16; c++) {
            floatx4 vv = vr[c];
            a += vv.x * wr[c].x + vv.y * wr[c].y + vv.z * wr[c].z + vv.w * wr[c].w;
        }
        out[((size_t)(bq * 64 + bb) * NH + h) * E_ + o] = a;
    }
}

// ---------------------------------------------------------------------------
// Kernel 4: out[b,r,o] = sigmoid(gate_lin) * tanh(fc_lin)
// fcv/gatev hoisted to registers (16+16 per thread); only broadcast ats reads
// in the r-loop.
// ---------------------------------------------------------------------------
__global__ __launch_bounds__(256)
void final_kernel(const float* __restrict__ fcv, const float* __restrict__ gatev,
                  const float* __restrict__ attnT, const float* __restrict__ fc_b,
                  const float* __restrict__ gate_b, float* __restrict__ out)
{
    const int b = blockIdx.x;
    const int tid = threadIdx.x;
    __shared__ float ats[NR * NH];

    ats[tid]       = attnT[(size_t)b * NR * NH + tid];
    ats[256 + tid] = attnT[(size_t)b * NR * NH + 256 + tid];

    float fr[2][8], gr[2][8];
#pragma unroll
    for (int half = 0; half < 2; half++) {
        int o = half * 256 + tid;
#pragma unroll
        for (int hh = 0; hh < 8; hh++) {
            fr[half][hh] = fcv[((size_t)b * NH + hh) * E_ + o];
            gr[half][hh] = gatev[((size_t)b * NH + hh) * E_ + o];
        }
    }
    float bfc0 = fc_b[tid],   bfc1 = fc_b[256 + tid];
    float bgt0 = gate_b[tid], bgt1 = gate_b[256 + tid];
    __syncthreads();

    for (int r = 0; r < NR; r++) {
        float a[8];
#pragma unroll
        for (int hh = 0; hh < 8; hh++) a[hh] = ats[r * NH + hh];
#pragma unroll
        for (int half = 0; half < 2; half++) {
            int o = half * 256 + tid;
            float fc = half ? bfc1 : bfc0;
            float gt = half ? bgt1 : bgt0;
#pragma unroll
            for (int hh = 0; hh < 8; hh++) {
                fc = fmaf(a[hh], fr[half][hh], fc);
                gt = fmaf(a[hh], gr[half][hh], gt);
            }
            float g = 1.f / (1.f + __expf(-gt));
            out[((size_t)(b * NR + r)) * E_ + o] = g * tanhf(fc);
        }
    }
}

// ---------------------------------------------------------------------------
extern "C" void kernel_launch(void* const* d_in, const int* in_sizes, int n_in,
                              void* d_out, int out_size, void* d_ws, size_t ws_size,
                              hipStream_t stream)
{
    const float* q      = (const float*)d_in[0];
    const float* k      = (const float*)d_in[1];
    const float* v      = (const float*)d_in[2];
    const float* Wq     = (const float*)d_in[3];
    const float* Wk     = (const float*)d_in[4];
    const float* Wv     = (const float*)d_in[5];
    const float* fc_w   = (const float*)d_in[6];
    const float* fc_b   = (const float*)d_in[7];
    const float* gate_w = (const float*)d_in[8];
    const float* gate_b = (const float*)d_in[9];
    float* out = (float*)d_out;

    // workspace layout (~73 MB)
    char* ws = (char*)d_ws;
    float* qp    = (float*)(ws);                               // 32 MB
    float* kp    = (float*)(ws + 33554432);                    // 32 MB
    float* vsum  = (float*)(ws + 67108864);                    // 512 KB
    float* attnT = (float*)(ws + 67108864 + 524288);           // 512 KB
    float* fcv   = (float*)(ws + 67108864 + 2 * 524288);       // 4 MB
    float* gatev = (float*)(ws + 67108864 + 2 * 524288 + 4194304); // 4 MB

    hipMemsetAsync(vsum, 0, 524288, stream);

    hipLaunchKernelGGL(proj_kernel, dim3(8, 64, 3), dim3(256), 0, stream,
                       q, k, v, Wq, Wk, Wv, qp, kp, vsum);
    hipLaunchKernelGGL(attn_kernel, dim3(2048), dim3(256), 0, stream, qp, kp, attnT);
    hipLaunchKernelGGL(fcv_kernel, dim3(8, 8, 2), dim3(256), 0, stream,
                       vsum, fc_w, gate_w, fcv, gatev);
    hipLaunchKernelGGL(final_kernel, dim3(256), dim3(256), 0, stream,
                       fcv, gatev, attnT, fc_b, gate_b, out);
}

// Round 4
// 380.741 us; speedup vs baseline: 1.2668x; 1.1194x over previous
//
#include <hip/hip_runtime.h>
#include <stdint.h>

// Problem constants (from reference)
#define B_    256
#define NR    64
#define NW    64
#define DIN   512
#define NH    8
#define DK    64
#define E_    512          // NH*DK
#define TEMP_INV 0.125f    // 1/sqrt(64)
#define EPSV  1e-7f

typedef unsigned short u16;
typedef unsigned int   u32;
typedef _Float16 f16;
typedef __attribute__((ext_vector_type(2))) float    floatx2;
typedef __attribute__((ext_vector_type(4))) float    floatx4;
typedef __attribute__((ext_vector_type(8))) short    shortx8;
typedef __attribute__((ext_vector_type(4))) u32      uintx4;
typedef __attribute__((ext_vector_type(2))) _Float16 halfx2;

__device__ __forceinline__ u32 asu(float f) { union { float f; u32 u; } c; c.f = f; return c.u; }
__device__ __forceinline__ float asf(u32 u) { union { u32 u; float f; } c; c.u = u; return c.f; }
// pack truncated-bf16 of (x,y): low16 = hi16(x), high16 = hi16(y)
__device__ __forceinline__ u32 packhi(float x, float y) {
    return (asu(x) >> 16) | (asu(y) & 0xFFFF0000u);
}
__device__ __forceinline__ float hi_of(float x) { return asf(asu(x) & 0xFFFF0000u); }
__device__ __forceinline__ halfx2 h2(u32 u) { union { u32 u; halfx2 h; } c; c.u = u; return c.h; }

#if __has_builtin(__builtin_amdgcn_fdot2)
#define FDOT2(a, b, c) __builtin_amdgcn_fdot2((a), (b), (c), false)
#else
__device__ __forceinline__ float FDOT2(halfx2 a, halfx2 b, float c) {
    return fmaf((float)a.y, (float)b.y, fmaf((float)a.x, (float)b.x, c));
}
#endif

// ---------------------------------------------------------------------------
// Kernel 1: grouped projection GEMM, split-bf16 (truncation split, ~2^-15).
// out[b,e] = sum_d X[b,n,d] * W[n,d,e].  z=0: q->qp(f16)  z=1: k->kp(f16)
// z=2: v -> atomicAdd vsum[b,e], hi-only bf16.
// LDS layout (padding-free, unit-major, all-b128, bank-balanced):
//   A[hi|lo]: [k-unit u(4)][row r(128)] x 16B      (element k: u=k>>3, j=k&7)
//   B[hi|lo]: [k-unit u(4)][e&1][e>>1(64)] x 16B
// XCD swizzle: all 8 tiles of (n,z) share blockIdx-linear % 8 -> same XCD L2.
// ---------------------------------------------------------------------------
__global__ __launch_bounds__(256)
void proj_kernel(const float* __restrict__ q, const float* __restrict__ kk_,
                 const float* __restrict__ v,
                 const float* __restrict__ Wq, const float* __restrict__ Wk,
                 const float* __restrict__ Wv,
                 f16* __restrict__ qp, f16* __restrict__ kp,
                 float* __restrict__ vsum)
{
    const float* X; const float* W; f16* dst = nullptr; bool vmode = false;
    if (blockIdx.z == 0)      { X = q;   W = Wq; dst = qp; }
    else if (blockIdx.z == 1) { X = kk_; W = Wk; dst = kp; }
    else                      { X = v;   W = Wv; vmode = true; }

    // XCD-locality remap: n determines id%8; t = tile (m0,n0)
    const int n  = blockIdx.x * 8 + (blockIdx.y & 7);
    const int t  = blockIdx.y >> 3;
    const int m0 = (t >> 2) * 128;
    const int n0 = (t & 3) * 128;

    __shared__ u16 Ah[4096];
    __shared__ u16 Al[4096];
    __shared__ u16 Bh[4096];
    __shared__ u16 Bl[4096];

    const int tid  = threadIdx.x;
    const int lane = tid & 63;
    const int wave = tid >> 6;
    const int wm   = (wave >> 1) * 64;
    const int wn   = (wave & 1) * 64;
    const int l15  = lane & 15;
    const int quad = lane >> 4;

    floatx4 acc[4][4];
#pragma unroll
    for (int i = 0; i < 4; i++)
#pragma unroll
        for (int j = 0; j < 4; j++) acc[i][j] = (floatx4){0.f, 0.f, 0.f, 0.f};

    // A: thread -> (row, k-half of 16)
    const int arow  = tid >> 1;
    const int ahalf = tid & 1;
    const float* aptr = X + ((size_t)(m0 + arow) * NW + n) * DIN + ahalf * 16;
    // B: thread -> 8k x 2e patch; kq == wave
    const int kq = tid >> 6;
    const int p  = tid & 63;
    const float* wptr = W + (size_t)n * (DIN * E_) + n0 + 2 * p;

    floatx4 pa[4]; floatx2 pb[8];
#pragma unroll
    for (int c = 0; c < 4; c++) pa[c] = *(const floatx4*)(aptr + c * 4);
#pragma unroll
    for (int j = 0; j < 8; j++) pb[j] = *(const floatx2*)(wptr + (size_t)(kq * 8 + j) * E_);

    for (int it = 0; it < 16; it++) {
        // ---- convert + b128 LDS stores from prefetched regs ----
        {
            u32 h[8], l[8];
#pragma unroll
            for (int c = 0; c < 4; c++) {
                h[2 * c]     = packhi(pa[c].x, pa[c].y);
                h[2 * c + 1] = packhi(pa[c].z, pa[c].w);
                float r0 = pa[c].x - hi_of(pa[c].x), r1 = pa[c].y - hi_of(pa[c].y);
                float r2 = pa[c].z - hi_of(pa[c].z), r3 = pa[c].w - hi_of(pa[c].w);
                l[2 * c]     = packhi(r0, r1);
                l[2 * c + 1] = packhi(r2, r3);
            }
            *(uintx4*)&Ah[(2 * ahalf + 0) * 1024 + arow * 8] = (uintx4){h[0], h[1], h[2], h[3]};
            *(uintx4*)&Ah[(2 * ahalf + 1) * 1024 + arow * 8] = (uintx4){h[4], h[5], h[6], h[7]};
            if (!vmode) {
                *(uintx4*)&Al[(2 * ahalf + 0) * 1024 + arow * 8] = (uintx4){l[0], l[1], l[2], l[3]};
                *(uintx4*)&Al[(2 * ahalf + 1) * 1024 + arow * 8] = (uintx4){l[4], l[5], l[6], l[7]};
            }
        }
#pragma unroll
        for (int eo = 0; eo < 2; eo++) {
            float x0 = pb[0][eo], x1 = pb[1][eo], x2 = pb[2][eo], x3 = pb[3][eo];
            float x4 = pb[4][eo], x5 = pb[5][eo], x6 = pb[6][eo], x7 = pb[7][eo];
            uintx4 hv = (uintx4){packhi(x0, x1), packhi(x2, x3), packhi(x4, x5), packhi(x6, x7)};
            *(uintx4*)&Bh[kq * 1024 + eo * 512 + p * 8] = hv;
            if (!vmode) {
                uintx4 lv = (uintx4){packhi(x0 - hi_of(x0), x1 - hi_of(x1)),
                                     packhi(x2 - hi_of(x2), x3 - hi_of(x3)),
                                     packhi(x4 - hi_of(x4), x5 - hi_of(x5)),
                                     packhi(x6 - hi_of(x6), x7 - hi_of(x7))};
                *(uintx4*)&Bl[kq * 1024 + eo * 512 + p * 8] = lv;
            }
        }

        // ---- issue next iteration's global loads (land during MFMA) ----
        if (it < 15) {
            const int kn = it * 32 + 32;
#pragma unroll
            for (int c = 0; c < 4; c++) pa[c] = *(const floatx4*)(aptr + kn + c * 4);
#pragma unroll
            for (int j = 0; j < 8; j++)
                pb[j] = *(const floatx2*)(wptr + (size_t)(kn + kq * 8 + j) * E_);
        }

        __syncthreads();

        shortx8 afh[4], afl[4], bfh[4], bfl[4];
#pragma unroll
        for (int mi = 0; mi < 4; mi++) {
            int R = wm + mi * 16 + l15;
            afh[mi] = *(const shortx8*)&Ah[quad * 1024 + R * 8];
            if (!vmode) afl[mi] = *(const shortx8*)&Al[quad * 1024 + R * 8];
        }
#pragma unroll
        for (int ni = 0; ni < 4; ni++) {
            int e = wn + ni * 16 + l15;
            int off = quad * 1024 + (e & 1) * 512 + (e >> 1) * 8;
            bfh[ni] = *(const shortx8*)&Bh[off];
            if (!vmode) bfl[ni] = *(const shortx8*)&Bl[off];
        }
#pragma unroll
        for (int mi = 0; mi < 4; mi++)
#pragma unroll
            for (int ni = 0; ni < 4; ni++) {
                acc[mi][ni] = __builtin_amdgcn_mfma_f32_16x16x32_bf16(
                    afh[mi], bfh[ni], acc[mi][ni], 0, 0, 0);
                if (!vmode) {
                    acc[mi][ni] = __builtin_amdgcn_mfma_f32_16x16x32_bf16(
                        afh[mi], bfl[ni], acc[mi][ni], 0, 0, 0);
                    acc[mi][ni] = __builtin_amdgcn_mfma_f32_16x16x32_bf16(
                        afl[mi], bfh[ni], acc[mi][ni], 0, 0, 0);
                }
            }
        __syncthreads();
    }

    // Epilogue: C/D layout col = lane&15, row = quad*4 + reg  [measured m89]
    if (!vmode) {
#pragma unroll
        for (int mi = 0; mi < 4; mi++) {
            int rowb = m0 + wm + mi * 16 + quad * 4;
#pragma unroll
            for (int ni = 0; ni < 4; ni++) {
                int col = n0 + wn + ni * 16 + l15;
#pragma unroll
                for (int r = 0; r < 4; r++)
                    dst[((size_t)(rowb + r) * NW + n) * E_ + col] = (f16)acc[mi][ni][r];
            }
        }
    } else {
#pragma unroll
        for (int mi = 0; mi < 4; mi++) {
            int rowb = m0 + wm + mi * 16 + quad * 4;
#pragma unroll
            for (int ni = 0; ni < 4; ni++) {
                int col = n0 + wn + ni * 16 + l15;
#pragma unroll
                for (int r = 0; r < 4; r++)
                    atomicAdd(&vsum[(size_t)(rowb + r) * E_ + col], acc[mi][ni][r]);
            }
        }
    }
}

// ---------------------------------------------------------------------------
// Kernel 2: per-(h,b): scores via fdot2 with q in regs (per-lane) and k rows
// via wave-uniform scalar loads (no LDS traffic). 4 waves; wave w handles
// l in [w*16, w*16+16); lane j owns query row j. Then wave 0: double-exp
// softmax over 64 rows + top-16 threshold.
// ---------------------------------------------------------------------------
__global__ __launch_bounds__(256)
void attn_kernel(const f16* __restrict__ qp, const f16* __restrict__ kp,
                 float* __restrict__ attnT)
{
    const int h = blockIdx.x >> 8;
    const int b = blockIdx.x & 255;
    __shared__ float mred[4][64];

    const int t    = threadIdx.x;
    const int w    = t >> 6;
    const int lane = t & 63;

    const f16* qrow = qp + ((size_t)(b * NR + lane)) * E_ + h * DK;
    halfx2 qreg[32];
#pragma unroll
    for (int c = 0; c < 8; c++) {
        uintx4 u = *(const uintx4*)(qrow + c * 8);
        qreg[c * 4 + 0] = h2(u.x); qreg[c * 4 + 1] = h2(u.y);
        qreg[c * 4 + 2] = h2(u.z); qreg[c * 4 + 3] = h2(u.w);
    }

    float m = -1e30f;
    for (int ll = 0; ll < 16; ll++) {
        int lu = __builtin_amdgcn_readfirstlane(w * 16 + ll);
        const u32* k32 = (const u32*)(kp + ((size_t)(b * NW + lu)) * E_ + h * DK);
        float a0 = 0.f, a1 = 0.f;
#pragma unroll
        for (int c = 0; c < 32; c += 2) {
            a0 = FDOT2(qreg[c],     h2(k32[c]),     a0);
            a1 = FDOT2(qreg[c + 1], h2(k32[c + 1]), a1);
        }
        m = fmaxf(m, a0 + a1);
    }
    mred[w][lane] = m;
    __syncthreads();

    if (t < 64) {   // wave 0 only
        float mm = fmaxf(fmaxf(mred[0][lane], mred[1][lane]),
                         fmaxf(mred[2][lane], mred[3][lane])) * TEMP_INV;
        float e = expf(mm);                      // a = exp(max score)
        float mx = e;
#pragma unroll
        for (int d = 1; d < 64; d <<= 1) mx = fmaxf(mx, __shfl_xor(mx, d));
        float tt = expf(e - mx);
        float S = tt;
#pragma unroll
        for (int d = 1; d < 64; d <<= 1) S += __shfl_xor(S, d);
        float s = tt / S;

        // k-th largest (k=16) via 16x (wave-max, mask first holder)
        float cur = s, v16 = 0.f;
        for (int itk = 0; itk < 16; itk++) {
            float mv = cur;
#pragma unroll
            for (int d = 1; d < 64; d <<= 1) mv = fmaxf(mv, __shfl_xor(mv, d));
            unsigned long long bal = __ballot(cur == mv);
            int first = __ffsll(bal) - 1;
            if (lane == first) cur = -1e30f;
            v16 = mv;
        }
        float delta = v16 + EPSV;
        float ww = fmaxf(s - delta, 0.f);
        float sw = ww;
#pragma unroll
        for (int d = 1; d < 64; d <<= 1) sw += __shfl_xor(sw, d);
        attnT[((size_t)b * NR + lane) * NH + h] = ww / (sw + EPSV);
    }
}

// ---------------------------------------------------------------------------
// Kernel 3: fcv[b,h,o] = sum_dv vsum[b, h*64+dv] * W[o, h*64+dv]
// grid (16: ohalf*8+bq, 8: h, 2: fc/gate), 32 b per block -> 256 blocks
// ---------------------------------------------------------------------------
__global__ __launch_bounds__(256)
void fcv_kernel(const float* __restrict__ vsum, const float* __restrict__ fc_w,
                const float* __restrict__ gate_w, float* __restrict__ fcv,
                float* __restrict__ gatev)
{
    const int ohalf = blockIdx.x >> 3;
    const int bq    = blockIdx.x & 7;
    const int h     = blockIdx.y;
    const float* W  = blockIdx.z ? gate_w : fc_w;
    float* out      = blockIdx.z ? gatev : fcv;
    const int o     = ohalf * 256 + threadIdx.x;

    __shared__ float vs[32 * 64];
#pragma unroll
    for (int i = 0; i < 8; i++) {
        int idx = i * 256 + threadIdx.x;
        int bb = idx >> 6, d = idx & 63;
        vs[idx] = vsum[(size_t)(bq * 32 + bb) * E_ + h * DK + d];
    }
    floatx4 wr[16];
#pragma unroll
    for (int c = 0; c < 16; c++)
        wr[c] = *(const floatx4*)(W + (size_t)o * E_ + h * DK + c * 4);
    __syncthreads();

    for (int bb = 0; bb < 32; bb++) {
        const floatx4* vr = (const floatx4*)&vs[bb * 64];
        float a = 0.f;
#pragma unroll
        for (int c = 0; c < 16; c++) {
            floatx4 vv = vr[c];
            a += vv.x * wr[c].x + vv.y * wr[c].y + vv.z * wr[c].z + vv.w * wr[c].w;
        }
        out[((size_t)(bq * 32 + bb) * NH + h) * E_ + o] = a;
    }
}

// ---------------------------------------------------------------------------
// Kernel 4: out[b,r,o] = sigmoid(gate_lin) * tanh(fc_lin)
// ---------------------------------------------------------------------------
__global__ __launch_bounds__(256)
void final_kernel(const float* __restrict__ fcv, const float* __restrict__ gatev,
                  const float* __restrict__ attnT, const float* __restrict__ fc_b,
                  const float* __restrict__ gate_b, float* __restrict__ out)
{
    const int b = blockIdx.x;
    const int tid = threadIdx.x;
    __shared__ float ats[NR * NH];

    ats[tid]       = attnT[(size_t)b * NR * NH + tid];
    ats[256 + tid] = attnT[(size_t)b * NR * NH + 256 + tid];

    float fr[2][8], gr[2][8];
#pragma unroll
    for (int half = 0; half < 2; half++) {
        int o = half * 256 + tid;
#pragma unroll
        for (int hh = 0; hh < 8; hh++) {
            fr[half][hh] = fcv[((size_t)b * NH + hh) * E_ + o];
            gr[half][hh] = gatev[((size_t)b * NH + hh) * E_ + o];
        }
    }
    float bfc0 = fc_b[tid],   bfc1 = fc_b[256 + tid];
    float bgt0 = gate_b[tid], bgt1 = gate_b[256 + tid];
    __syncthreads();

    for (int r = 0; r < NR; r++) {
        float a[8];
#pragma unroll
        for (int hh = 0; hh < 8; hh++) a[hh] = ats[r * NH + hh];
#pragma unroll
        for (int half = 0; half < 2; half++) {
            int o = half * 256 + tid;
            float fc = half ? bfc1 : bfc0;
            float gt = half ? bgt1 : bgt0;
#pragma unroll
            for (int hh = 0; hh < 8; hh++) {
                fc = fmaf(a[hh], fr[half][hh], fc);
                gt = fmaf(a[hh], gr[half][hh], gt);
            }
            float g  = 1.f / (1.f + __expf(-gt));
            float e2 = __expf(2.f * fc);
            float th = 1.f - 2.f / (e2 + 1.f);
            out[((size_t)(b * NR + r)) * E_ + o] = g * th;
        }
    }
}

// ---------------------------------------------------------------------------
extern "C" void kernel_launch(void* const* d_in, const int* in_sizes, int n_in,
                              void* d_out, int out_size, void* d_ws, size_t ws_size,
                              hipStream_t stream)
{
    const float* q      = (const float*)d_in[0];
    const float* k      = (const float*)d_in[1];
    const float* v      = (const float*)d_in[2];
    const float* Wq     = (const float*)d_in[3];
    const float* Wk     = (const float*)d_in[4];
    const float* Wv     = (const float*)d_in[5];
    const float* fc_w   = (const float*)d_in[6];
    const float* fc_b   = (const float*)d_in[7];
    const float* gate_w = (const float*)d_in[8];
    const float* gate_b = (const float*)d_in[9];
    float* out = (float*)d_out;

    // workspace layout (~42 MB)
    char* ws = (char*)d_ws;
    f16*   qp    = (f16*)(ws);                                 // 16 MB
    f16*   kp    = (f16*)(ws + 16777216);                      // 16 MB
    float* vsum  = (float*)(ws + 33554432);                    // 512 KB
    float* attnT = (float*)(ws + 33554432 + 524288);           // 512 KB
    float* fcv   = (float*)(ws + 33554432 + 2 * 524288);       // 4 MB
    float* gatev = (float*)(ws + 33554432 + 2 * 524288 + 4194304); // 4 MB

    hipMemsetAsync(vsum, 0, 524288, stream);

    hipLaunchKernelGGL(proj_kernel, dim3(8, 64, 3), dim3(256), 0, stream,
                       q, k, v, Wq, Wk, Wv, qp, kp, vsum);
    hipLaunchKernelGGL(attn_kernel, dim3(2048), dim3(256), 0, stream, qp, kp, attnT);
    hipLaunchKernelGGL(fcv_kernel, dim3(16, 8, 2), dim3(256), 0, stream,
                       vsum, fc_w, gate_w, fcv, gatev);
    hipLaunchKernelGGL(final_kernel, dim3(256), dim3(256), 0, stream,
                       fcv, gatev, attnT, fc_b, gate_b, out);
}

// Round 5
// 379.559 us; speedup vs baseline: 1.2708x; 1.0031x over previous
//
#include <hip/hip_runtime.h>
#include <stdint.h>

// Problem constants (from reference)
#define B_    256
#define NR    64
#define NW    64
#define DIN   512
#define NH    8
#define DK    64
#define E_    512          // NH*DK
#define TEMP_INV 0.125f    // 1/sqrt(64)
#define EPSV  1e-7f

typedef unsigned short u16;
typedef unsigned int   u32;
typedef _Float16 f16;
typedef __attribute__((ext_vector_type(2))) float    floatx2;
typedef __attribute__((ext_vector_type(4))) float    floatx4;
typedef __attribute__((ext_vector_type(4))) u32      uintx4;
typedef __attribute__((ext_vector_type(2))) _Float16 halfx2;
typedef __attribute__((ext_vector_type(8))) _Float16 halfx8;

__device__ __forceinline__ u32 asu(float f) { union { float f; u32 u; } c; c.f = f; return c.u; }
__device__ __forceinline__ halfx2 h2(u32 u) { union { u32 u; halfx2 h; } c; c.u = u; return c.h; }
// pack two fp32 -> f16x2 dword (RNE via v_cvt_f16_f32 + pack)
__device__ __forceinline__ u32 pkh(float a, float b) {
    union { halfx2 h; u32 u; } c; c.h = (halfx2){(f16)a, (f16)b}; return c.u;
}

#if __has_builtin(__builtin_amdgcn_fdot2)
#define FDOT2(a, b, c) __builtin_amdgcn_fdot2((a), (b), (c), false)
#else
__device__ __forceinline__ float FDOT2(halfx2 a, halfx2 b, float c) {
    return fmaf((float)a.y, (float)b.y, fmaf((float)a.x, (float)b.x, c));
}
#endif

// ---------------------------------------------------------------------------
// Kernel 1: grouped projection GEMM, f16 MFMA (fp32 accumulate).
// out[b,e] = sum_d X[b,n,d] * W[n,d,e].  z=0: q->qp(f16)  z=1: k->kp(f16)
// z=2: v -> atomicAdd vsum[b,e] (fp32).
// f16 inputs (2^-12 rms rounding) keep total error ~2-3e-3 vs 1.03e-2 budget
// (r1 evidence: bf16=2^-9 gave 1.17e-2; error scales ~linearly in input eps).
// LDS layout (padding-free, unit-major, all-b128, bank-balanced, 8-phase min):
//   A: [k-unit u(4)][row r(128)] x 16B      (element k: u=k>>3, j=k&7)
//   B: [k-unit u(4)][e&1][e>>1(64)] x 16B
// XCD swizzle: all 8 tiles of (n,z) share blockIdx-linear % 8 -> same XCD L2.
// ---------------------------------------------------------------------------
__global__ __launch_bounds__(256)
void proj_kernel(const float* __restrict__ q, const float* __restrict__ kk_,
                 const float* __restrict__ v,
                 const float* __restrict__ Wq, const float* __restrict__ Wk,
                 const float* __restrict__ Wv,
                 f16* __restrict__ qp, f16* __restrict__ kp,
                 float* __restrict__ vsum)
{
    const float* X; const float* W; f16* dst = nullptr; bool vmode = false;
    if (blockIdx.z == 0)      { X = q;   W = Wq; dst = qp; }
    else if (blockIdx.z == 1) { X = kk_; W = Wk; dst = kp; }
    else                      { X = v;   W = Wv; vmode = true; }

    // XCD-locality remap: n determines id%8; t = tile (m0,n0)
    const int n  = blockIdx.x * 8 + (blockIdx.y & 7);
    const int t  = blockIdx.y >> 3;
    const int m0 = (t >> 2) * 128;
    const int n0 = (t & 3) * 128;

    __shared__ u16 As[4096];
    __shared__ u16 Bs[4096];

    const int tid  = threadIdx.x;
    const int lane = tid & 63;
    const int wave = tid >> 6;
    const int wm   = (wave >> 1) * 64;
    const int wn   = (wave & 1) * 64;
    const int l15  = lane & 15;
    const int quad = lane >> 4;

    floatx4 acc[4][4];
#pragma unroll
    for (int i = 0; i < 4; i++)
#pragma unroll
        for (int j = 0; j < 4; j++) acc[i][j] = (floatx4){0.f, 0.f, 0.f, 0.f};

    // A: thread -> (row, k-half of 16)
    const int arow  = tid >> 1;
    const int ahalf = tid & 1;
    const float* aptr = X + ((size_t)(m0 + arow) * NW + n) * DIN + ahalf * 16;
    // B: thread -> 8k x 2e patch; kq == wave
    const int kq = tid >> 6;
    const int p  = tid & 63;
    const float* wptr = W + (size_t)n * (DIN * E_) + n0 + 2 * p;

    floatx4 pa[4]; floatx2 pb[8];
#pragma unroll
    for (int c = 0; c < 4; c++) pa[c] = *(const floatx4*)(aptr + c * 4);
#pragma unroll
    for (int j = 0; j < 8; j++) pb[j] = *(const floatx2*)(wptr + (size_t)(kq * 8 + j) * E_);

    for (int it = 0; it < 16; it++) {
        // ---- convert fp32->f16, b128 LDS stores from prefetched regs ----
        {
            u32 h[8];
#pragma unroll
            for (int c = 0; c < 4; c++) {
                h[2 * c]     = pkh(pa[c].x, pa[c].y);
                h[2 * c + 1] = pkh(pa[c].z, pa[c].w);
            }
            *(uintx4*)&As[(2 * ahalf + 0) * 1024 + arow * 8] = (uintx4){h[0], h[1], h[2], h[3]};
            *(uintx4*)&As[(2 * ahalf + 1) * 1024 + arow * 8] = (uintx4){h[4], h[5], h[6], h[7]};
        }
#pragma unroll
        for (int eo = 0; eo < 2; eo++) {
            uintx4 hv = (uintx4){pkh(pb[0][eo], pb[1][eo]), pkh(pb[2][eo], pb[3][eo]),
                                 pkh(pb[4][eo], pb[5][eo]), pkh(pb[6][eo], pb[7][eo])};
            *(uintx4*)&Bs[kq * 1024 + eo * 512 + p * 8] = hv;
        }

        // ---- issue next iteration's global loads (land during MFMA) ----
        if (it < 15) {
            const int kn = it * 32 + 32;
#pragma unroll
            for (int c = 0; c < 4; c++) pa[c] = *(const floatx4*)(aptr + kn + c * 4);
#pragma unroll
            for (int j = 0; j < 8; j++)
                pb[j] = *(const floatx2*)(wptr + (size_t)(kn + kq * 8 + j) * E_);
        }

        __syncthreads();

        halfx8 af[4], bf[4];
#pragma unroll
        for (int mi = 0; mi < 4; mi++) {
            int R = wm + mi * 16 + l15;
            af[mi] = *(const halfx8*)&As[quad * 1024 + R * 8];
        }
#pragma unroll
        for (int ni = 0; ni < 4; ni++) {
            int e = wn + ni * 16 + l15;
            bf[ni] = *(const halfx8*)&Bs[quad * 1024 + (e & 1) * 512 + (e >> 1) * 8];
        }
#pragma unroll
        for (int mi = 0; mi < 4; mi++)
#pragma unroll
            for (int ni = 0; ni < 4; ni++)
                acc[mi][ni] = __builtin_amdgcn_mfma_f32_16x16x32_f16(
                    af[mi], bf[ni], acc[mi][ni], 0, 0, 0);
        __syncthreads();
    }

    // Epilogue: C/D layout col = lane&15, row = quad*4 + reg  [measured m89]
    if (!vmode) {
#pragma unroll
        for (int mi = 0; mi < 4; mi++) {
            int rowb = m0 + wm + mi * 16 + quad * 4;
#pragma unroll
            for (int ni = 0; ni < 4; ni++) {
                int col = n0 + wn + ni * 16 + l15;
#pragma unroll
                for (int r = 0; r < 4; r++)
                    dst[((size_t)(rowb + r) * NW + n) * E_ + col] = (f16)acc[mi][ni][r];
            }
        }
    } else {
#pragma unroll
        for (int mi = 0; mi < 4; mi++) {
            int rowb = m0 + wm + mi * 16 + quad * 4;
#pragma unroll
            for (int ni = 0; ni < 4; ni++) {
                int col = n0 + wn + ni * 16 + l15;
#pragma unroll
                for (int r = 0; r < 4; r++)
                    atomicAdd(&vsum[(size_t)(rowb + r) * E_ + col], acc[mi][ni][r]);
            }
        }
    }
}

// ---------------------------------------------------------------------------
// Kernel 2: per-(h,b): scores via fdot2 with q in regs (per-lane) and k rows
// via wave-uniform loads (no LDS traffic). 4 waves; wave w handles
// l in [w*16, w*16+16); lane j owns query row j. Then wave 0: double-exp
// softmax over 64 rows + top-16 threshold.   [UNCHANGED from r4]
// ---------------------------------------------------------------------------
__global__ __launch_bounds__(256)
void attn_kernel(const f16* __restrict__ qp, const f16* __restrict__ kp,
                 float* __restrict__ attnT)
{
    const int h = blockIdx.x >> 8;
    const int b = blockIdx.x & 255;
    __shared__ float mred[4][64];

    const int t    = threadIdx.x;
    const int w    = t >> 6;
    const int lane = t & 63;

    const f16* qrow = qp + ((size_t)(b * NR + lane)) * E_ + h * DK;
    halfx2 qreg[32];
#pragma unroll
    for (int c = 0; c < 8; c++) {
        uintx4 u = *(const uintx4*)(qrow + c * 8);
        qreg[c * 4 + 0] = h2(u.x); qreg[c * 4 + 1] = h2(u.y);
        qreg[c * 4 + 2] = h2(u.z); qreg[c * 4 + 3] = h2(u.w);
    }

    float m = -1e30f;
    for (int ll = 0; ll < 16; ll++) {
        int lu = __builtin_amdgcn_readfirstlane(w * 16 + ll);
        const u32* k32 = (const u32*)(kp + ((size_t)(b * NW + lu)) * E_ + h * DK);
        float a0 = 0.f, a1 = 0.f;
#pragma unroll
        for (int c = 0; c < 32; c += 2) {
            a0 = FDOT2(qreg[c],     h2(k32[c]),     a0);
            a1 = FDOT2(qreg[c + 1], h2(k32[c + 1]), a1);
        }
        m = fmaxf(m, a0 + a1);
    }
    mred[w][lane] = m;
    __syncthreads();

    if (t < 64) {   // wave 0 only
        float mm = fmaxf(fmaxf(mred[0][lane], mred[1][lane]),
                         fmaxf(mred[2][lane], mred[3][lane])) * TEMP_INV;
        float e = expf(mm);                      // a = exp(max score)
        float mx = e;
#pragma unroll
        for (int d = 1; d < 64; d <<= 1) mx = fmaxf(mx, __shfl_xor(mx, d));
        float tt = expf(e - mx);
        float S = tt;
#pragma unroll
        for (int d = 1; d < 64; d <<= 1) S += __shfl_xor(S, d);
        float s = tt / S;

        // k-th largest (k=16) via 16x (wave-max, mask first holder)
        float cur = s, v16 = 0.f;
        for (int itk = 0; itk < 16; itk++) {
            float mv = cur;
#pragma unroll
            for (int d = 1; d < 64; d <<= 1) mv = fmaxf(mv, __shfl_xor(mv, d));
            unsigned long long bal = __ballot(cur == mv);
            int first = __ffsll(bal) - 1;
            if (lane == first) cur = -1e30f;
            v16 = mv;
        }
        float delta = v16 + EPSV;
        float ww = fmaxf(s - delta, 0.f);
        float sw = ww;
#pragma unroll
        for (int d = 1; d < 64; d <<= 1) sw += __shfl_xor(sw, d);
        attnT[((size_t)b * NR + lane) * NH + h] = ww / (sw + EPSV);
    }
}

// ---------------------------------------------------------------------------
// Kernel 3: fcv[b,h,o] = sum_dv vsum[b, h*64+dv] * W[o, h*64+dv]
// grid (16: ohalf*8+bq, 8: h, 2: fc/gate)   [UNCHANGED from r4]
// ---------------------------------------------------------------------------
__global__ __launch_bounds__(256)
void fcv_kernel(const float* __restrict__ vsum, const float* __restrict__ fc_w,
                const float* __restrict__ gate_w, float* __restrict__ fcv,
                float* __restrict__ gatev)
{
    const int ohalf = blockIdx.x >> 3;
    const int bq    = blockIdx.x & 7;
    const int h     = blockIdx.y;
    const float* W  = blockIdx.z ? gate_w : fc_w;
    float* out      = blockIdx.z ? gatev : fcv;
    const int o     = ohalf * 256 + threadIdx.x;

    __shared__ float vs[32 * 64];
#pragma unroll
    for (int i = 0; i < 8; i++) {
        int idx = i * 256 + threadIdx.x;
        int bb = idx >> 6, d = idx & 63;
        vs[idx] = vsum[(size_t)(bq * 32 + bb) * E_ + h * DK + d];
    }
    floatx4 wr[16];
#pragma unroll
    for (int c = 0; c < 16; c++)
        wr[c] = *(const floatx4*)(W + (size_t)o * E_ + h * DK + c * 4);
    __syncthreads();

    for (int bb = 0; bb < 32; bb++) {
        const floatx4* vr = (const floatx4*)&vs[bb * 64];
        float a = 0.f;
#pragma unroll
        for (int c = 0; c < 16; c++) {
            floatx4 vv = vr[c];
            a += vv.x * wr[c].x + vv.y * wr[c].y + vv.z * wr[c].z + vv.w * wr[c].w;
        }
        out[((size_t)(bq * 32 + bb) * NH + h) * E_ + o] = a;
    }
}

// ---------------------------------------------------------------------------
// Kernel 4: out[b,r,o] = sigmoid(gate_lin) * tanh(fc_lin)  [UNCHANGED from r4]
// ---------------------------------------------------------------------------
__global__ __launch_bounds__(256)
void final_kernel(const float* __restrict__ fcv, const float* __restrict__ gatev,
                  const float* __restrict__ attnT, const float* __restrict__ fc_b,
                  const float* __restrict__ gate_b, float* __restrict__ out)
{
    const int b = blockIdx.x;
    const int tid = threadIdx.x;
    __shared__ float ats[NR * NH];

    ats[tid]       = attnT[(size_t)b * NR * NH + tid];
    ats[256 + tid] = attnT[(size_t)b * NR * NH + 256 + tid];

    float fr[2][8], gr[2][8];
#pragma unroll
    for (int half = 0; half < 2; half++) {
        int o = half * 256 + tid;
#pragma unroll
        for (int hh = 0; hh < 8; hh++) {
            fr[half][hh] = fcv[((size_t)b * NH + hh) * E_ + o];
            gr[half][hh] = gatev[((size_t)b * NH + hh) * E_ + o];
        }
    }
    float bfc0 = fc_b[tid],   bfc1 = fc_b[256 + tid];
    float bgt0 = gate_b[tid], bgt1 = gate_b[256 + tid];
    __syncthreads();

    for (int r = 0; r < NR; r++) {
        float a[8];
#pragma unroll
        for (int hh = 0; hh < 8; hh++) a[hh] = ats[r * NH + hh];
#pragma unroll
        for (int half = 0; half < 2; half++) {
            int o = half * 256 + tid;
            float fc = half ? bfc1 : bfc0;
            float gt = half ? bgt1 : bgt0;
#pragma unroll
            for (int hh = 0; hh < 8; hh++) {
                fc = fmaf(a[hh], fr[half][hh], fc);
                gt = fmaf(a[hh], gr[half][hh], gt);
            }
            float g  = 1.f / (1.f + __expf(-gt));
            float e2 = __expf(2.f * fc);
            float th = 1.f - 2.f / (e2 + 1.f);
            out[((size_t)(b * NR + r)) * E_ + o] = g * th;
        }
    }
}

// ---------------------------------------------------------------------------
extern "C" void kernel_launch(void* const* d_in, const int* in_sizes, int n_in,
                              void* d_out, int out_size, void* d_ws, size_t ws_size,
                              hipStream_t stream)
{
    const float* q      = (const float*)d_in[0];
    const float* k      = (const float*)d_in[1];
    const float* v      = (const float*)d_in[2];
    const float* Wq     = (const float*)d_in[3];
    const float* Wk     = (const float*)d_in[4];
    const float* Wv     = (const float*)d_in[5];
    const float* fc_w   = (const float*)d_in[6];
    const float* fc_b   = (const float*)d_in[7];
    const float* gate_w = (const float*)d_in[8];
    const float* gate_b = (const float*)d_in[9];
    float* out = (float*)d_out;

    // workspace layout (~42 MB)
    char* ws = (char*)d_ws;
    f16*   qp    = (f16*)(ws);                                 // 16 MB
    f16*   kp    = (f16*)(ws + 16777216);                      // 16 MB
    float* vsum  = (float*)(ws + 33554432);                    // 512 KB
    float* attnT = (float*)(ws + 33554432 + 524288);           // 512 KB
    float* fcv   = (float*)(ws + 33554432 + 2 * 524288);       // 4 MB
    float* gatev = (float*)(ws + 33554432 + 2 * 524288 + 4194304); // 4 MB

    hipMemsetAsync(vsum, 0, 524288, stream);

    hipLaunchKernelGGL(proj_kernel, dim3(8, 64, 3), dim3(256), 0, stream,
                       q, k, v, Wq, Wk, Wv, qp, kp, vsum);
    hipLaunchKernelGGL(attn_kernel, dim3(2048), dim3(256), 0, stream, qp, kp, attnT);
    hipLaunchKernelGGL(fcv_kernel, dim3(16, 8, 2), dim3(256), 0, stream,
                       vsum, fc_w, gate_w, fcv, gatev);
    hipLaunchKernelGGL(final_kernel, dim3(256), dim3(256), 0, stream,
                       fcv, gatev, attnT, fc_b, gate_b, out);
}